// Round 1
// baseline (204.811 us; speedup 1.0000x reference)
//
#include <hip/hip_runtime.h>
#include <math.h>

#define EXTRA_COE 0.5f
#define ROWS_PER_BLOCK 4   // 4 waves of 64, one wave per row

// Kernel 1: one wave (64 lanes) per row. Each lane streams 4 float4s per
// embedding (coalesced: lane i reads vec index j*64+i), accumulates
// sum((a-p)^2) and sum((a-n)^2), butterfly-reduces across the wave, lane 0
// computes the row loss, block reduces 4 waves in LDS, writes one partial
// per block into d_ws.
__global__ __launch_bounds__(256) void st_loss_rows(
    const float* __restrict__ ea, const float* __restrict__ ep,
    const float* __restrict__ en, const float* __restrict__ td,
    const int* __restrict__ bidx, float* __restrict__ partial,
    int B, int D)
{
    const int wave = threadIdx.x >> 6;
    const int lane = threadIdx.x & 63;
    const int row  = blockIdx.x * ROWS_PER_BLOCK + wave;

    float row_loss = 0.0f;
    if (row < B) {
        const size_t base = (size_t)row * (size_t)D;
        const float4* a4 = (const float4*)(ea + base);
        const float4* p4 = (const float4*)(ep + base);
        const float4* n4 = (const float4*)(en + base);
        const int nvec = D >> 2;   // 256 for D=1024

        float s_ap = 0.0f, s_an = 0.0f;
        for (int j = lane; j < nvec; j += 64) {
            float4 av = a4[j];
            float4 pv = p4[j];
            float4 nv = n4[j];
            float dx = av.x - pv.x, dy = av.y - pv.y,
                  dz = av.z - pv.z, dw = av.w - pv.w;
            s_ap += dx*dx + dy*dy + dz*dz + dw*dw;
            dx = av.x - nv.x; dy = av.y - nv.y;
            dz = av.z - nv.z; dw = av.w - nv.w;
            s_an += dx*dx + dy*dy + dz*dz + dw*dw;
        }
        // 64-lane butterfly reduction
        #pragma unroll
        for (int off = 32; off >= 1; off >>= 1) {
            s_ap += __shfl_xor(s_ap, off, 64);
            s_an += __shfl_xor(s_an, off, 64);
        }
        if (lane == 0) {
            const float v_ap = expf(-sqrtf(s_ap));
            const float v_an = expf(-sqrtf(s_an));
            const int idx = bidx[row];
            const float d0 = td[2 * idx + 0] * EXTRA_COE;
            const float d1 = td[2 * idx + 1] * EXTRA_COE;
            const float D_ap = expf(-d0);
            const float D_an = expf(-d1);
            float l = (D_ap - v_ap) * (D_ap - v_ap)
                    + (D_an - v_an) * (D_an - v_an);
            if (D_ap > D_an) {
                float m = v_an - v_ap;
                m = m > 0.0f ? m : 0.0f;
                l += m * m;
            }
            row_loss = l;
        }
    }

    __shared__ float sm[ROWS_PER_BLOCK];
    if (lane == 0) sm[wave] = row_loss;
    __syncthreads();
    if (threadIdx.x == 0) {
        float s = 0.0f;
        #pragma unroll
        for (int w = 0; w < ROWS_PER_BLOCK; ++w) s += sm[w];
        partial[blockIdx.x] = s;
    }
}

// Kernel 2: reduce the per-block partials and write the mean.
__global__ __launch_bounds__(256) void st_loss_final(
    const float* __restrict__ partial, int n_partial,
    float* __restrict__ out, float inv_b)
{
    float s = 0.0f;
    for (int i = threadIdx.x; i < n_partial; i += 256) s += partial[i];
    #pragma unroll
    for (int off = 32; off >= 1; off >>= 1) s += __shfl_xor(s, off, 64);
    __shared__ float sm[4];
    if ((threadIdx.x & 63) == 0) sm[threadIdx.x >> 6] = s;
    __syncthreads();
    if (threadIdx.x == 0) out[0] = (sm[0] + sm[1] + sm[2] + sm[3]) * inv_b;
}

extern "C" void kernel_launch(void* const* d_in, const int* in_sizes, int n_in,
                              void* d_out, int out_size, void* d_ws, size_t ws_size,
                              hipStream_t stream) {
    const float* ea   = (const float*)d_in[0];
    const float* ep   = (const float*)d_in[1];
    const float* en   = (const float*)d_in[2];
    const float* td   = (const float*)d_in[3];
    const int*   bidx = (const int*)d_in[4];
    float* out = (float*)d_out;

    const int B = in_sizes[4];                 // 16384 rows
    const int D = in_sizes[0] / B;             // 1024
    const int n_blocks = (B + ROWS_PER_BLOCK - 1) / ROWS_PER_BLOCK;

    float* partial = (float*)d_ws;             // n_blocks floats

    st_loss_rows<<<n_blocks, 256, 0, stream>>>(ea, ep, en, td, bidx,
                                               partial, B, D);
    st_loss_final<<<1, 256, 0, stream>>>(partial, n_blocks, out, 1.0f / (float)B);
}

// Round 2
// 200.765 us; speedup vs baseline: 1.0202x; 1.0202x over previous
//
#include <hip/hip_runtime.h>
#include <math.h>

#define EXTRA_COE 0.5f
#define ROWS_PER_BLOCK 4   // 4 waves of 64, one wave per row

// D=1024 fast path: one wave per row. Each lane owns 4 float4s per stream
// (lane + 64*k, k=0..3). ALL 12 global_load_dwordx4 are issued before any
// consumption -> 12 KB in flight per wave (vs ~3 KB with the runtime-trip
// loop), attacking the latency/MLP bound seen in R1 (VALUBusy 8%, 2.6 TB/s).
__global__ __launch_bounds__(256) void st_loss_rows_1024(
    const float* __restrict__ ea, const float* __restrict__ ep,
    const float* __restrict__ en, const float* __restrict__ td,
    const int* __restrict__ bidx, float* __restrict__ partial, int B)
{
    const int wave = threadIdx.x >> 6;
    const int lane = threadIdx.x & 63;
    const int row  = blockIdx.x * ROWS_PER_BLOCK + wave;

    float row_loss = 0.0f;
    if (row < B) {
        const size_t base = (size_t)row * 1024u;
        const float4* a4 = (const float4*)(ea + base);
        const float4* p4 = (const float4*)(ep + base);
        const float4* n4 = (const float4*)(en + base);

        float4 av[4], pv[4], nv[4];
        #pragma unroll
        for (int k = 0; k < 4; ++k) av[k] = a4[lane + 64 * k];
        #pragma unroll
        for (int k = 0; k < 4; ++k) pv[k] = p4[lane + 64 * k];
        #pragma unroll
        for (int k = 0; k < 4; ++k) nv[k] = n4[lane + 64 * k];

        float s_ap = 0.0f, s_an = 0.0f;
        #pragma unroll
        for (int k = 0; k < 4; ++k) {
            float dx = av[k].x - pv[k].x, dy = av[k].y - pv[k].y,
                  dz = av[k].z - pv[k].z, dw = av[k].w - pv[k].w;
            s_ap += dx*dx + dy*dy + dz*dz + dw*dw;
            dx = av[k].x - nv[k].x; dy = av[k].y - nv[k].y;
            dz = av[k].z - nv[k].z; dw = av[k].w - nv[k].w;
            s_an += dx*dx + dy*dy + dz*dz + dw*dw;
        }

        #pragma unroll
        for (int off = 32; off >= 1; off >>= 1) {
            s_ap += __shfl_xor(s_ap, off, 64);
            s_an += __shfl_xor(s_an, off, 64);
        }
        if (lane == 0) {
            const float v_ap = expf(-sqrtf(s_ap));
            const float v_an = expf(-sqrtf(s_an));
            const int idx = bidx[row];
            const float d0 = td[2 * idx + 0] * EXTRA_COE;
            const float d1 = td[2 * idx + 1] * EXTRA_COE;
            const float D_ap = expf(-d0);
            const float D_an = expf(-d1);
            float l = (D_ap - v_ap) * (D_ap - v_ap)
                    + (D_an - v_an) * (D_an - v_an);
            if (D_ap > D_an) {
                float m = v_an - v_ap;
                m = m > 0.0f ? m : 0.0f;
                l += m * m;
            }
            row_loss = l;
        }
    }

    __shared__ float sm[ROWS_PER_BLOCK];
    if (lane == 0) sm[wave] = row_loss;
    __syncthreads();
    if (threadIdx.x == 0) {
        float s = 0.0f;
        #pragma unroll
        for (int w = 0; w < ROWS_PER_BLOCK; ++w) s += sm[w];
        partial[blockIdx.x] = s;
    }
}

// Generic-D fallback (same structure as R1).
__global__ __launch_bounds__(256) void st_loss_rows_gen(
    const float* __restrict__ ea, const float* __restrict__ ep,
    const float* __restrict__ en, const float* __restrict__ td,
    const int* __restrict__ bidx, float* __restrict__ partial,
    int B, int D)
{
    const int wave = threadIdx.x >> 6;
    const int lane = threadIdx.x & 63;
    const int row  = blockIdx.x * ROWS_PER_BLOCK + wave;

    float row_loss = 0.0f;
    if (row < B) {
        const size_t base = (size_t)row * (size_t)D;
        const float4* a4 = (const float4*)(ea + base);
        const float4* p4 = (const float4*)(ep + base);
        const float4* n4 = (const float4*)(en + base);
        const int nvec = D >> 2;

        float s_ap = 0.0f, s_an = 0.0f;
        for (int j = lane; j < nvec; j += 64) {
            float4 av = a4[j], pv = p4[j], nv = n4[j];
            float dx = av.x - pv.x, dy = av.y - pv.y,
                  dz = av.z - pv.z, dw = av.w - pv.w;
            s_ap += dx*dx + dy*dy + dz*dz + dw*dw;
            dx = av.x - nv.x; dy = av.y - nv.y;
            dz = av.z - nv.z; dw = av.w - nv.w;
            s_an += dx*dx + dy*dy + dz*dz + dw*dw;
        }
        #pragma unroll
        for (int off = 32; off >= 1; off >>= 1) {
            s_ap += __shfl_xor(s_ap, off, 64);
            s_an += __shfl_xor(s_an, off, 64);
        }
        if (lane == 0) {
            const float v_ap = expf(-sqrtf(s_ap));
            const float v_an = expf(-sqrtf(s_an));
            const int idx = bidx[row];
            const float d0 = td[2 * idx + 0] * EXTRA_COE;
            const float d1 = td[2 * idx + 1] * EXTRA_COE;
            const float D_ap = expf(-d0);
            const float D_an = expf(-d1);
            float l = (D_ap - v_ap) * (D_ap - v_ap)
                    + (D_an - v_an) * (D_an - v_an);
            if (D_ap > D_an) {
                float m = v_an - v_ap;
                m = m > 0.0f ? m : 0.0f;
                l += m * m;
            }
            row_loss = l;
        }
    }

    __shared__ float sm[ROWS_PER_BLOCK];
    if (lane == 0) sm[wave] = row_loss;
    __syncthreads();
    if (threadIdx.x == 0) {
        float s = 0.0f;
        #pragma unroll
        for (int w = 0; w < ROWS_PER_BLOCK; ++w) s += sm[w];
        partial[blockIdx.x] = s;
    }
}

__global__ __launch_bounds__(256) void st_loss_final(
    const float* __restrict__ partial, int n_partial,
    float* __restrict__ out, float inv_b)
{
    float s = 0.0f;
    for (int i = threadIdx.x; i < n_partial; i += 256) s += partial[i];
    #pragma unroll
    for (int off = 32; off >= 1; off >>= 1) s += __shfl_xor(s, off, 64);
    __shared__ float sm[4];
    if ((threadIdx.x & 63) == 0) sm[threadIdx.x >> 6] = s;
    __syncthreads();
    if (threadIdx.x == 0) out[0] = (sm[0] + sm[1] + sm[2] + sm[3]) * inv_b;
}

extern "C" void kernel_launch(void* const* d_in, const int* in_sizes, int n_in,
                              void* d_out, int out_size, void* d_ws, size_t ws_size,
                              hipStream_t stream) {
    const float* ea   = (const float*)d_in[0];
    const float* ep   = (const float*)d_in[1];
    const float* en   = (const float*)d_in[2];
    const float* td   = (const float*)d_in[3];
    const int*   bidx = (const int*)d_in[4];
    float* out = (float*)d_out;

    const int B = in_sizes[4];                 // 16384 rows
    const int D = in_sizes[0] / B;             // 1024
    const int n_blocks = (B + ROWS_PER_BLOCK - 1) / ROWS_PER_BLOCK;

    float* partial = (float*)d_ws;             // n_blocks floats

    if (D == 1024) {
        st_loss_rows_1024<<<n_blocks, 256, 0, stream>>>(ea, ep, en, td, bidx,
                                                        partial, B);
    } else {
        st_loss_rows_gen<<<n_blocks, 256, 0, stream>>>(ea, ep, en, td, bidx,
                                                       partial, B, D);
    }
    st_loss_final<<<1, 256, 0, stream>>>(partial, n_blocks, out, 1.0f / (float)B);
}